// Round 9
// baseline (131.106 us; speedup 1.0000x reference)
//
#include <hip/hip_runtime.h>

// MoE: out[b,:] = sum_e softmax(gate(x))[b,e] * (W3_e^T @ relu(W2_e^T @ relu(W1_e^T @ x_b + b1) + b2) + b3)
// R17: REFORMULATED on 32x32x16 f16 MFMA -- 32 tokens per tile (was 16 via 16x16).
//      Rationale: R12-R16 showed wall time ~ (tiles/SIMD) x ~constant per-tile latency/overhead
//      (~2300 cyc/tile) with no pipe saturated; ILP widening (R14) and load pipelining (R16)
//      were null. Halving tile count per token is the remaining lever: 43 MFMAs now cover 32
//      tokens instead of 16 (MFMA/DS/gate/epilogue/loop overhead all halve per token),
//      tiles/SIMD 64 -> 32.
//      Layout (derived from HW-verified facts):
//        C/D: col = lane&31 (token), row = (reg&3) + 8*(reg>>2) + 4*(lane>>5)  [m74/m101]
//        A/B: m|n = lane&31, k = 4*(lane>>5) + (j&3) + 8*(j>>2)  (two K8 blocks -- exact
//             analog of the verified two-K16-block structure of 16x16x32 used in R2-R16)
//      => C/D -> next layer's B is IN-LANE with NO permutation: B elems j0..3 = C regs 0..3,
//         j4..7 = regs 4..7 (lo K-block); regs 8..15 (hi block). K=32 layers = 2 chained MFMAs.
//      L1: one MFMA, bias b1 in A at k=6, x B-frag: h=0:{x0..x3}, h=1:{x4,x5,1,0}, elems 4-7=0.
//      L2: 2 MFMAs, b2 as f32 C-init from LDS table (rows m=(reg&3)+8(reg>>2)+4h).
//      L3: 2 MFMAs/expert, A block-diag rows m=2e+o (<16), zeros baked in LDS image; ALL
//          Y regs 0-7 carry real (e,o), regs 8-15 stay 0. b3 folded into epilogue adds.
//      Gate: 1+2 MFMAs, logits rows 0-7 -> lane halves hold e0-3 / e4-7; softmax exchange =
//          ONE shfl_xor(32) of a packed f16 pair; out store by lanes<32 (32 tokens).
//      waves_per_eu(2,2): proven cap 128 arch + 128 acc (R9-R16 model). 512 blocks x 4 waves
//      = 2048 waves x 16 tiles of 32 tokens = exact fill, zero tail.
//      Falsifiable: absmax <= 0.0156 (layout check); WRITE_SIZE stays 8.19 MB (no spills).

typedef _Float16 half2_t __attribute__((ext_vector_type(2)));
typedef _Float16 half8_t __attribute__((ext_vector_type(8)));
typedef __fp16   fp16v2  __attribute__((ext_vector_type(2)));
typedef float  f32x16   __attribute__((ext_vector_type(16)));
typedef float  float4_t __attribute__((ext_vector_type(4)));
typedef float  float2_t __attribute__((ext_vector_type(2)));
typedef int    int4_t   __attribute__((ext_vector_type(4)));

#define MFMA32(A, B, C) __builtin_amdgcn_mfma_f32_32x32x16_f16((A), (B), (C), 0, 0, 0)

static constexpr int E_ = 8, DIN_ = 6, H_ = 32;

union H8U { half2_t h2[4]; half8_t h8; int4_t i4; };
union HI  { half2_t h; int i; };
union PKU { fp16v2 p; half2_t h; };
union C16 { f32x16 v; float4_t q[4]; };

__device__ __forceinline__ half2_t pkrtz(float a, float b) {
    PKU u; u.p = __builtin_amdgcn_cvt_pkrtz(a, b);
    return u.h;
}

__device__ __forceinline__ half2_t relu2(half2_t v) {
    const half2_t z = {(_Float16)0.0f, (_Float16)0.0f};
    return __builtin_elementwise_max(v, z);
}

__global__ __launch_bounds__(256)
__attribute__((amdgpu_waves_per_eu(2, 2)))
void moe_kernel(
    const float* __restrict__ x,  const float* __restrict__ W1, const float* __restrict__ b1,
    const float* __restrict__ W2, const float* __restrict__ b2, const float* __restrict__ W3,
    const float* __restrict__ b3, const float* __restrict__ Wg1, const float* __restrict__ bg1,
    const float* __restrict__ Wg2, const float* __restrict__ bg2,
    float* __restrict__ out, int nTok, int nTiles, int tilesPerWave)
{
    const int tid  = threadIdx.x;
    const int lane = tid & 63;
    const int m    = lane & 31;   // A-row / token-column index
    const int h    = lane >> 5;   // lane half: K sub-block selector
    const int wv   = tid >> 6;    // wave in block
    const int gw   = (blockIdx.x << 2) + wv;   // global wave id (waves independent)

    // block-uniform weight images (pi-free 32x32 layouts)
    __shared__ H8U w1img[E_][64];        //  8 KB: L1 A-frag (k=features, bias at k=6)
    __shared__ H8U w2img[E_][2][64];     // 16 KB: L2 A-frag, K-blocks lo/hi
    __shared__ H8U a3img[E_][2][64];     // 16 KB: L3 A-frag, block-diag rows m=2e+o, zeros baked
    __shared__ float b2s[E_][H_];        //  1 KB: b2 rows for f32 C-init

    const float L2E = 1.44269504f;
    const half2_t h2z = pkrtz(0.f, 0.f);

    // ---- build expert images: wave wv packs experts {2wv, 2wv+1}
    #pragma unroll
    for (int j = 0; j < 2; ++j) {
        const int e = wv * 2 + j;
        H8U w1v;
        if (h == 0) {
            w1v.h2[0] = pkrtz(W1[(e*DIN_+0)*H_+m], W1[(e*DIN_+1)*H_+m]);
            w1v.h2[1] = pkrtz(W1[(e*DIN_+2)*H_+m], W1[(e*DIN_+3)*H_+m]);
        } else {
            w1v.h2[0] = pkrtz(W1[(e*DIN_+4)*H_+m], W1[(e*DIN_+5)*H_+m]);
            w1v.h2[1] = pkrtz(b1[e*H_+m], 0.f);          // k=6 bias slot; k=7 zero
        }
        w1v.h2[2] = h2z; w1v.h2[3] = h2z;                // k>=8 zero
        w1img[e][lane] = w1v;

        const int o = m & 1;
        const bool alive = ((m >> 1) == e);              // rows m=2e+o only (m<16)
        #pragma unroll
        for (int b = 0; b < 2; ++b) {
            H8U w2v, a3v;
            #pragma unroll
            for (int p = 0; p < 4; ++p) {
                const int k0 = 16*b + 8*(p>>1) + 4*h + 2*(p&1);
                w2v.h2[p] = pkrtz(W2[(e*H_+k0)*H_+m], W2[(e*H_+k0+1)*H_+m]);
                a3v.h2[p] = alive ? pkrtz(W3[(e*H_+k0)*2+o], W3[(e*H_+k0+1)*2+o]) : h2z;
            }
            w2img[e][b][lane] = w2v;
            a3img[e][b][lane] = a3v;
        }
        if (lane < H_) b2s[e][lane] = b2[e*H_ + lane];
    }

    // ---- persistent gate fragments (per-lane, built direct from global)
    H8U G1;
    if (h == 0) {
        G1.h2[0] = pkrtz(Wg1[0*H_+m], Wg1[1*H_+m]);
        G1.h2[1] = pkrtz(Wg1[2*H_+m], Wg1[3*H_+m]);
    } else {
        G1.h2[0] = pkrtz(Wg1[4*H_+m], Wg1[5*H_+m]);
        G1.h2[1] = pkrtz(bg1[m], 0.f);
    }
    G1.h2[2] = h2z; G1.h2[3] = h2z;

    H8U G2[2];
    {
        const bool alive = (m < E_);                     // logits rows 0..7 only
        #pragma unroll
        for (int b = 0; b < 2; ++b)
            #pragma unroll
            for (int p = 0; p < 4; ++p) {
                const int k0 = 16*b + 8*(p>>1) + 4*h + 2*(p&1);
                G2[b].h2[p] = alive ? pkrtz(Wg2[k0*E_+m]*L2E, Wg2[(k0+1)*E_+m]*L2E) : h2z;
            }
    }
    float4_t bg2F;
    #pragma unroll
    for (int r = 0; r < 4; ++r) bg2F[r] = bg2[4*h + r] * L2E;   // logit rows 4h+r (<8)

    float b3P[8];                                         // Y reg r -> row (r&3)+8*(r>>2)+4h < 16
    #pragma unroll
    for (int r = 0; r < 8; ++r) b3P[r] = b3[(r&3) + 8*(r>>2) + 4*h];

    const f32x16 z16 = {0,0,0,0, 0,0,0,0, 0,0,0,0, 0,0,0,0};
    const float4_t z4 = {0.f, 0.f, 0.f, 0.f};

    __syncthreads();   // images ready; NO barriers inside the loop

    const int tile0 = gw * tilesPerWave;
    const int xo1 = h ? 4 : 0;
    const int xo2 = h ? 4 : 2;
    const float* xq = x + ((size_t)tile0 * 32 + m) * DIN_;
    float2_t la = {0.f, 0.f}, lb = {0.f, 0.f};
    if (tile0 < nTiles && (size_t)tile0 * 32 + m < (size_t)nTok) {
        la = *(const float2_t*)(xq + xo1);
        lb = *(const float2_t*)(xq + xo2);
    }
    HI onei; onei.h = pkrtz(1.f, 0.f);

    for (int it = 0; it < tilesPerWave; ++it) {
        const int tile = tile0 + it;
        if (tile >= nTiles) break;          // uniform per wave
        const bool tok = ((size_t)tile * 32 + m) < (size_t)nTok;

        // x B-frag: h=0: {x0..x3, 0..}; h=1: {x4,x5,1,0, 0..}
        H8U xB;
        xB.h2[0] = pkrtz(la[0], la[1]);
        { HI hb; hb.h = pkrtz(lb[0], lb[1]); HI se; se.i = h ? onei.i : hb.i; xB.h2[1] = se.h; }
        xB.h2[2] = h2z; xB.h2[3] = h2z;

        // prefetch next tile's x
        if (it + 1 < tilesPerWave && tile + 1 < nTiles) {
            const float* xn = xq + (size_t)(it + 1) * 32 * DIN_;
            if ((size_t)(tile + 1) * 32 + m < (size_t)nTok) {
                la = *(const float2_t*)(xn + xo1);
                lb = *(const float2_t*)(xn + xo2);
            }
        }

        // ---- gate: 3 MFMAs; logits land in regs 0-3 (rows 4h+0..3 = experts 4h+0..3)
        f32x16 hg = MFMA32(G1.h8, xB.h8, z16);
        H8U uhlo, uhhi;
        #pragma unroll
        for (int i = 0; i < 4; ++i) {
            uhlo.h2[i] = relu2(pkrtz(hg[2*i],   hg[2*i+1]));
            uhhi.h2[i] = relu2(pkrtz(hg[8+2*i], hg[8+2*i+1]));
        }
        C16 gc; gc.q[0] = bg2F; gc.q[1] = z4; gc.q[2] = z4; gc.q[3] = z4;
        f32x16 gl = MFMA32(G2[0].h8, uhlo.h8, gc.v);
        gl = MFMA32(G2[1].h8, uhhi.h8, gl);

        // softmax over 8 experts (no max-sub; log2 domain), normalization deferred
        float ex0 = __builtin_amdgcn_exp2f(gl[0]);
        float ex1 = __builtin_amdgcn_exp2f(gl[1]);
        float ex2 = __builtin_amdgcn_exp2f(gl[2]);
        float ex3 = __builtin_amdgcn_exp2f(gl[3]);
        float s = (ex0 + ex1) + (ex2 + ex3);
        s += __shfl_xor(s, 32);
        float rs = __builtin_amdgcn_rcpf(s);
        // exchange: h=0 sends (e2,e3), h=1 sends (e4,e5); one packed shfl_xor(32)
        float sA = h ? ex0 : ex2, sB = h ? ex1 : ex3;
        HI sp; sp.h = pkrtz(sA, sB);
        HI rp; rp.i = __shfl_xor(sp.i, 32);
        float rA = (float)rp.h[0], rB = (float)rp.h[1];
        // weights for this lane's Y regs: h=0 rows {e0,e1,e4,e5}; h=1 rows {e2,e3,e6,e7}
        float wA = h ? rA : ex0, wB = h ? rB : ex1;
        float wC = h ? ex2 : rA, wD = h ? ex3 : rB;

        // ---- all 8 experts: 5 MFMAs each, Y accumulated block-diagonally
        f32x16 Y = z16;
        #pragma unroll
        for (int e = 0; e < E_; ++e) {
            H8U a1; a1.i4 = w1img[e][lane].i4;
            f32x16 c1 = MFMA32(a1.h8, xB.h8, z16);
            H8U u1lo, u1hi;
            #pragma unroll
            for (int i = 0; i < 4; ++i) {
                u1lo.h2[i] = relu2(pkrtz(c1[2*i],   c1[2*i+1]));
                u1hi.h2[i] = relu2(pkrtz(c1[8+2*i], c1[8+2*i+1]));
            }
            H8U a2lo, a2hi;
            a2lo.i4 = w2img[e][0][lane].i4;
            a2hi.i4 = w2img[e][1][lane].i4;
            C16 bc;
            bc.q[0] = *(const float4_t*)&b2s[e][4*h];
            bc.q[1] = *(const float4_t*)&b2s[e][8 + 4*h];
            bc.q[2] = *(const float4_t*)&b2s[e][16 + 4*h];
            bc.q[3] = *(const float4_t*)&b2s[e][24 + 4*h];
            f32x16 c2 = MFMA32(a2lo.h8, u1lo.h8, bc.v);     // b2 in f32 C-init
            c2 = MFMA32(a2hi.h8, u1hi.h8, c2);
            H8U u2lo, u2hi;
            #pragma unroll
            for (int i = 0; i < 4; ++i) {
                u2lo.h2[i] = relu2(pkrtz(c2[2*i],   c2[2*i+1]));
                u2hi.h2[i] = relu2(pkrtz(c2[8+2*i], c2[8+2*i+1]));
            }
            H8U a3lo, a3hi;
            a3lo.i4 = a3img[e][0][lane].i4;
            a3hi.i4 = a3img[e][1][lane].i4;
            Y = MFMA32(a3lo.h8, u2lo.h8, Y);
            Y = MFMA32(a3hi.h8, u2hi.h8, Y);
        }

        // ---- epilogue: Y regs 0-7 = rows {4h..4h+3, 8+4h..8+4h+3} = (e,o) pairs; b3 folded
        float p0 = wA*(Y[0]+b3P[0]) + wB*(Y[2]+b3P[2]) + wC*(Y[4]+b3P[4]) + wD*(Y[6]+b3P[6]);
        float p1 = wA*(Y[1]+b3P[1]) + wB*(Y[3]+b3P[3]) + wC*(Y[5]+b3P[5]) + wD*(Y[7]+b3P[7]);
        p0 += __shfl_xor(p0, 32);
        p1 += __shfl_xor(p1, 32);
        if (h == 0 && tok) {
            float2_t ov = {p0 * rs, p1 * rs};
            *(float2_t*)(out + ((size_t)tile * 32 + m) * 2) = ov;
        }
    }
}

extern "C" void kernel_launch(void* const* d_in, const int* in_sizes, int n_in,
                              void* d_out, int out_size, void* d_ws, size_t ws_size,
                              hipStream_t stream) {
    const float* x   = (const float*)d_in[0];
    const float* W1  = (const float*)d_in[1];
    const float* b1  = (const float*)d_in[2];
    const float* W2  = (const float*)d_in[3];
    const float* b2  = (const float*)d_in[4];
    const float* W3  = (const float*)d_in[5];
    const float* b3  = (const float*)d_in[6];
    const float* Wg1 = (const float*)d_in[7];
    const float* bg1 = (const float*)d_in[8];
    const float* Wg2 = (const float*)d_in[9];
    const float* bg2 = (const float*)d_in[10];
    float* out = (float*)d_out;

    const int B      = in_sizes[0] / DIN_;
    const int nTiles = (B + 31) / 32;
    // waves_per_eu(2,2): arch 128 + acc 128 (proven split). 512 blocks x 4 waves = 2048 waves
    // = exact 2 waves/SIMD; 41 KB LDS x 2 blocks/CU = 82 KB <= 160. 32768 tiles / 2048 waves
    // = 16 tiles of 32 tokens per wave, zero tail at B=1M.
    const int blocks = 512;
    const int wavesTotal = blocks * 4;
    const int tpw = (nTiles + wavesTotal - 1) / wavesTotal;

    moe_kernel<<<blocks, 256, 0, stream>>>(x, W1, b1, W2, b2, W3, b3,
                                           Wg1, bg1, Wg2, bg2, out, B, nTiles, tpw);
}